// Round 9
// baseline (1243.692 us; speedup 1.0000x reference)
//
#include <hip/hip_runtime.h>
#include <hip/hip_bf16.h>
#include <math.h>

// Round 9: round 8 + LDS-staged coalesced xg epilogue (fixes partial-line store amplification).
//  ace_front2: branches+QKV+attn+Wo+LN via MFMA; LN -> FLAT8 LDS -> one dwordx4/thread to xg.
//  ace_mlp:    proven MFMA MLP (round 3/5).
// B=131072, E=64, H=4, D=16, S=5. Out: (B,160) fp32.

#define NROWS 131072
#define BROWS 128

typedef __attribute__((ext_vector_type(8))) short short8;
typedef __attribute__((ext_vector_type(4))) float f32x4;

__device__ __forceinline__ short f2bs(float f) {
  __hip_bfloat16 h = __float2bfloat16(f);
  return *reinterpret_cast<short*>(&h);
}
__device__ __forceinline__ float bs2f(short s) {
  union { unsigned u; float f; } c;
  c.u = ((unsigned)(unsigned short)s) << 16;
  return c.f;
}

#define MFMA __builtin_amdgcn_mfma_f32_16x16x32_bf16
#define GLOAD_LDS16(g, l) __builtin_amdgcn_global_load_lds( \
    (const __attribute__((address_space(1))) void*)(g),     \
    (__attribute__((address_space(3))) void*)(l), 16, 0, 0)

// ---------------- pack 1: W1,W2 -> bf16 fragment-ordered (proven) ----------------
__global__ void pack_weights(const float* __restrict__ W1, const float* __restrict__ W2,
                             short* __restrict__ ws) {
  int idx = blockIdx.x * blockDim.x + threadIdx.x;
  if (idx < 81920) {
    int i = idx & 7, lane = (idx >> 3) & 63;
    int t = idx >> 9;                 // ntg*10 + kk
    int kk = t % 10, ntg = t / 10;
    int n = ntg * 16 + (lane & 15);
    int k = kk * 32 + (lane >> 4) * 8 + i;
    ws[idx] = f2bs(W1[k * 256 + n]);
  } else if (idx < 81920 + 40960) {
    int j = idx - 81920;
    int i = j & 7, lane = (j >> 3) & 63;
    int t = j >> 9;                   // ntg*8 + kk
    int kk = t & 7, ntg = t >> 3;
    int n = ntg * 16 + (lane & 15);
    int k = kk * 32 + (lane >> 4) * 8 + i;
    ws[81920 + j] = f2bs(W2[k * 160 + n]);
  }
}

// ---------------- pack 2: front weight tables (proven round 7) ----------------
__global__ void pack2(
    const float* __restrict__ Wv_p, const float* __restrict__ Wa_p,
    const float* __restrict__ Wp_p, const float* __restrict__ Ws_p,
    const float* __restrict__ Wt_p,
    const float* __restrict__ bv_p, const float* __restrict__ ba_p,
    const float* __restrict__ bp_p, const float* __restrict__ bs_p,
    const float* __restrict__ bt_p,
    const float* __restrict__ Wv_u, const float* __restrict__ Wa_u,
    const float* __restrict__ Wp_u, const float* __restrict__ Ws_u,
    const float* __restrict__ Wt_u,
    const float* __restrict__ bv_u, const float* __restrict__ ba_u,
    const float* __restrict__ bp_u, const float* __restrict__ bs_u,
    const float* __restrict__ bt_u,
    const float* __restrict__ Wq, const float* __restrict__ Wk,
    const float* __restrict__ Wvv,
    const float* __restrict__ bq, const float* __restrict__ bk,
    const float* __restrict__ bvv,
    const float* __restrict__ Wo, const float* __restrict__ bo,
    short* __restrict__ wsb, float* __restrict__ fb)
{
  int idx = blockIdx.x * blockDim.x + threadIdx.x;
  const float* WP[5] = {Wv_p, Wa_p, Wp_p, Ws_p, Wt_p};
  const float* BP[5] = {bv_p, ba_p, bp_p, bs_p, bt_p};
  const float* WU[5] = {Wv_u, Wa_u, Wp_u, Ws_u, Wt_u};
  const float* BU[5] = {bv_u, ba_u, bp_u, bs_u, bt_u};
  const int INs[5]  = {14, 17, 51, 7, 10};
  const int HIDs[5] = {32, 64, 32, 16, 16};
  const int KOFF[5] = {0, 16, 36, 92, 100};
  const int HOFF[5] = {0, 32, 96, 128, 144};

  if (idx < 20480) {                                   // WPbf
    int i = idx & 7, lane = (idx >> 3) & 63, rest = idx >> 9;   // rest<40
    int kt = rest / 10, ct = rest % 10;
    int k = kt * 32 + (lane >> 4) * 8 + i;
    int n = ct * 16 + (lane & 15);
    int s = (n < 32) ? 0 : (n < 96) ? 1 : (n < 128) ? 2 : (n < 144) ? 3 : 4;
    int kr = k - KOFF[s], nr = n - HOFF[s];
    float v = (kr >= 0 && kr < INs[s]) ? WP[s][kr * HIDs[s] + nr] : 0.f;
    wsb[122880 + idx] = f2bs(v);
  } else if (idx < 71680) {                            // WUbf
    int j2 = idx - 20480;
    int i = j2 & 7, lane = (j2 >> 3) & 63, rest = j2 >> 9;      // rest<100
    int kt = rest / 20, ct = rest % 20;
    int j = kt * 32 + (lane >> 4) * 8 + i;
    int c = ct * 16 + (lane & 15);
    int s = c >> 6, e = c & 63;
    int jr = j - HOFF[s];
    float v = (jr >= 0 && jr < HIDs[s]) ? WU[s][jr * 64 + e] : 0.f;
    wsb[143360 + j2] = f2bs(v);
  } else if (idx < 225280) {                           // WFbf
    int j2 = idx - 71680;
    int i = j2 & 7, lane = (j2 >> 3) & 63, rest = j2 >> 9;      // rest<300
    int kt = rest / 60, ct = rest % 60;
    int j = kt * 32 + (lane >> 4) * 8 + i;
    int c = ct * 16 + (lane & 15);
    int s = c / 192; int rem = c - s * 192; int t = rem >> 6, hd = rem & 63;
    int jr = j - HOFF[s];
    float v = 0.f;
    if (jr >= 0 && jr < HIDs[s]) {
      const float* wt = (t == 0) ? Wq : (t == 1) ? Wk : Wvv;
      float acc = 0.f;
      for (int e = 0; e < 64; ++e) acc += WU[s][jr * 64 + e] * wt[e * 64 + hd];
      v = acc;
    }
    wsb[194560 + j2] = f2bs(v);
  } else if (idx < 229376) {                           // WObf
    int j2 = idx - 225280;
    int i = j2 & 7, lane = (j2 >> 3) & 63, rest = j2 >> 9;      // rest<8
    int kt = rest >> 2, ct = rest & 3;
    int hd = kt * 32 + (lane >> 4) * 8 + i;
    int e = ct * 16 + (lane & 15);
    wsb[348160 + j2] = f2bs(Wo[hd * 64 + e]);
  } else if (idx < 229536) {                           // bpbig
    int n = idx - 229376;
    int s = (n < 32) ? 0 : (n < 96) ? 1 : (n < 128) ? 2 : (n < 144) ? 3 : 4;
    fb[n] = BP[s][n - HOFF[s]];
  } else if (idx < 230496) {                           // bqkvb
    int c = idx - 229536;
    int s = c / 192, rem = c % 192, t = rem >> 6, hd = rem & 63;
    const float* wt = (t == 0) ? Wq : (t == 1) ? Wk : Wvv;
    const float* bt = (t == 0) ? bq : (t == 1) ? bk : bvv;
    float acc = bt[hd];
    for (int e = 0; e < 64; ++e) acc += BU[s][e] * wt[e * 64 + hd];
    fb[160 + c] = acc;
  } else if (idx < 230816) {                           // bres
    int c = idx - 230496;
    int s = c >> 6, e = c & 63;
    fb[1120 + c] = BU[s][e] + bo[e];
  }
}

// ================= kernel A: MFMA front, 49KB LDS, coalesced epilogue =================
__global__ __launch_bounds__(320, 4) void ace_front2(
    const float* __restrict__ visual, const float* __restrict__ audio,
    const float* __restrict__ pose,   const float* __restrict__ spatial,
    const float* __restrict__ timex,
    const float* __restrict__ gamma, const float* __restrict__ beta,
    const short* __restrict__ WS, const float* __restrict__ FB,
    char* __restrict__ xg)   // bf16 [NROWS][320], byte (col*2)^((row&7)<<4)
{
  __shared__ char smem[50176];
  char* INb   = smem;            // [64][256B] bf16 (swz row&7), staging+proj
  char* QKV8  = smem;            // [8][1920B] bf16 (swz row&7), overlays INb
  char* O8    = smem + 15360;    // [40][128B] bf16 (swz row&7)
  char* Hb    = smem + 20480;    // [64][384B] bf16 (swz row&7; 384 = 3*128 bijective)
  char* FLAT8 = smem + 45056;    // [8][640B]  bf16 (swz row&7), LN out -> coalesced copy

  const short* WPbf = WS + 122880;
  const short* WUbf = WS + 143360;
  const short* WFbf = WS + 194560;
  const short* WObf = WS + 348160;
  const float* bpbig = FB;
  const float* bqkvb = FB + 160;
  const float* bres  = FB + 1120;

  const int tid  = threadIdx.x;
  const int wv   = tid >> 6;          // 0..4 == token s
  const int lane = tid & 63;
  const int r15  = lane & 15, g4 = lane >> 4;
  const int rowBase = blockIdx.x * 64;

  // ---------- zero IN ----------
  for (int i = tid; i < 4096; i += 320) ((float*)INb)[i] = 0.f;
  __syncthreads();
  // ---------- stage inputs (f32 global -> bf16 LDS, swizzled) ----------
  {
    const float* SRC[5] = {visual, audio, pose, spatial, timex};
    const int C[5] = {14, 17, 51, 7, 10};
    const int KO[5] = {0, 16, 36, 92, 100};
    #pragma unroll
    for (int md = 0; md < 5; ++md) {
      const float* src = SRC[md];
      const int c = C[md], ko = KO[md];
      for (int i = tid; i < 64 * c; i += 320) {
        int row = i / c, col = i - row * c;
        *(short*)(INb + row * 256 + (((ko + col) * 2) ^ ((row & 7) << 4))) =
            f2bs(src[(size_t)(rowBase + row) * c + col]);
      }
    }
  }
  __syncthreads();

  // ---------- proj: H[64][160] = relu(IN @ WPbig + bp) ----------
  {
    #pragma unroll
    for (int cc = 0; cc < 2; ++cc) {
      const int ct = wv * 2 + cc;
      const int pk0 = (ct < 6) ? 0 : (ct < 8) ? 1 : (ct == 8) ? 2 : 3;
      const int pk1 = (ct < 2) ? 1 : (ct < 6) ? 2 : (ct < 8) ? 3 : 4;
      f32x4 acc[4] = {};
      for (int kk = pk0; kk < pk1; ++kk) {
        short8 b = *(const short8*)(WPbf + ((kk * 10 + ct) * 64 + lane) * 8);
        #pragma unroll
        for (int mt = 0; mt < 4; ++mt) {
          int row = mt * 16 + r15;
          short8 a = *(const short8*)(INb + row * 256 + ((kk * 64 + g4 * 16) ^ ((row & 7) << 4)));
          acc[mt] = MFMA(a, b, acc[mt], 0, 0, 0);
        }
      }
      const int n = ct * 16 + r15;
      const float bias = bpbig[n];
      #pragma unroll
      for (int mt = 0; mt < 4; ++mt)
        #pragma unroll
        for (int j = 0; j < 4; ++j) {
          int row = mt * 16 + 4 * g4 + j;
          *(short*)(Hb + row * 384 + ((n * 2) ^ ((row & 7) << 4))) =
              f2bs(fmaxf(acc[mt][j] + bias, 0.f));
        }
    }
  }
  __syncthreads();

  // ---------- per-wave preloads ----------
  const int kt0 = (wv == 0) ? 0 : (wv == 1) ? 1 : (wv == 2) ? 3 : 4;
  const int kt1 = (wv == 0) ? 1 : (wv == 1) ? 3 : (wv == 2) ? 4 : 5;
  const int rs8 = (wv == 4) ? 7 : 2 * wv;
  const int re8 = rs8 + ((wv < 3) ? 2 : 1);
  float qb[12], bres_r[4], gam[4], bet[4];
  #pragma unroll
  for (int tt = 0; tt < 12; ++tt) qb[tt] = bqkvb[wv * 192 + tt * 16 + r15];
  #pragma unroll
  for (int et = 0; et < 4; ++et) {
    bres_r[et] = bres[wv * 64 + et * 16 + r15];
    gam[et] = gamma[et * 16 + r15];
    bet[et] = beta[et * 16 + r15];
  }

  // ---------- eighth loop: 8 rows each {ups+QKV | attn | Wo+LN | copy} ----------
  for (int e8 = 0; e8 < 8; ++e8) {
    f32x4 xa[4] = {};       // x fragments (rows e8*8+4g4+j valid for g4<2)
    {
      f32x4 qa[12] = {};
      for (int kk = kt0; kk < kt1; ++kk) {
        int arow = (e8 * 8 + r15) & 63;   // rows >63 wrap -> garbage, C rows 8..15 discarded
        short8 a = *(const short8*)(Hb + arow * 384 + ((kk * 64 + g4 * 16) ^ ((arow & 7) << 4)));
        #pragma unroll
        for (int et = 0; et < 4; ++et) {
          short8 b = *(const short8*)(WUbf + ((kk * 20 + wv * 4 + et) * 64 + lane) * 8);
          xa[et] = MFMA(a, b, xa[et], 0, 0, 0);
        }
        #pragma unroll
        for (int tt = 0; tt < 12; ++tt) {
          short8 b = *(const short8*)(WFbf + ((kk * 60 + wv * 12 + tt) * 64 + lane) * 8);
          qa[tt] = MFMA(a, b, qa[tt], 0, 0, 0);
        }
      }
      if (g4 < 2) {
        #pragma unroll
        for (int tt = 0; tt < 12; ++tt) {
          int col2 = (wv * 192 + tt * 16 + r15) * 2;
          #pragma unroll
          for (int j = 0; j < 4; ++j) {
            int r = 4 * g4 + j;
            *(short*)(QKV8 + r * 1920 + (col2 ^ ((r & 7) << 4))) = f2bs(qa[tt][j] + qb[tt]);
          }
        }
      }
    }
    __syncthreads();

    // attention (lane = h*16+d), rows split {2,2,2,1,1}
    for (int r = rs8; r < re8; ++r) {
      const char* rp = QKV8 + r * 1920;
      const int sw = (r & 7) << 4;
      float q[5], k[5], v[5];
      #pragma unroll
      for (int s2 = 0; s2 < 5; ++s2) {
        q[s2] = bs2f(*(const short*)(rp + (((s2 * 192 + lane) * 2) ^ sw)));
        k[s2] = bs2f(*(const short*)(rp + (((s2 * 192 + 64 + lane) * 2) ^ sw)));
        v[s2] = bs2f(*(const short*)(rp + (((s2 * 192 + 128 + lane) * 2) ^ sw)));
      }
      #pragma unroll
      for (int qi = 0; qi < 5; ++qi) {
        float sc[5];
        #pragma unroll
        for (int ki = 0; ki < 5; ++ki) {
          float p = q[qi] * k[ki];
          p += __shfl_xor(p, 1); p += __shfl_xor(p, 2);
          p += __shfl_xor(p, 4); p += __shfl_xor(p, 8);
          sc[ki] = p * 0.25f;
        }
        float mx = fmaxf(fmaxf(fmaxf(sc[0], sc[1]), fmaxf(sc[2], sc[3])), sc[4]);
        float ss = 0.f;
        #pragma unroll
        for (int ki = 0; ki < 5; ++ki) { sc[ki] = __expf(sc[ki] - mx); ss += sc[ki]; }
        float o = 0.f;
        #pragma unroll
        for (int ki = 0; ki < 5; ++ki) o += sc[ki] * v[ki];
        o /= ss;
        int orow = r * 5 + qi;
        *(short*)(O8 + orow * 128 + ((lane * 2) ^ ((orow & 7) << 4))) = f2bs(o);
      }
    }
    __syncthreads();

    // Wo: attended frags for token wv (A rows with r15>=8 read garbage; C rows 8..15 discarded)
    f32x4 af[4] = {};
    #pragma unroll
    for (int kk = 0; kk < 2; ++kk) {
      int orow = r15 * 5 + wv;
      short8 a = *(const short8*)(O8 + orow * 128 + ((kk * 64 + g4 * 16) ^ ((orow & 7) << 4)));
      #pragma unroll
      for (int et = 0; et < 4; ++et) {
        short8 b = *(const short8*)(WObf + ((kk * 4 + et) * 64 + lane) * 8);
        af[et] = MFMA(a, b, af[et], 0, 0, 0);
      }
    }
    // residual + LayerNorm -> FLAT8 (local rows 4g4+j, g4<2; local row == global row & 7)
    if (g4 < 2) {
      #pragma unroll
      for (int j = 0; j < 4; ++j) {
        float h[4], s1 = 0.f, s2 = 0.f;
        #pragma unroll
        for (int et = 0; et < 4; ++et) {
          h[et] = xa[et][j] + af[et][j] + bres_r[et];
          s1 += h[et]; s2 += h[et] * h[et];
        }
        s1 += __shfl_xor(s1, 1); s2 += __shfl_xor(s2, 1);
        s1 += __shfl_xor(s1, 2); s2 += __shfl_xor(s2, 2);
        s1 += __shfl_xor(s1, 4); s2 += __shfl_xor(s2, 4);
        s1 += __shfl_xor(s1, 8); s2 += __shfl_xor(s2, 8);
        float mean = s1 * 0.015625f;
        float var  = s2 * 0.015625f - mean * mean;
        float rs = rsqrtf(var + 1e-3f);
        int r = 4 * g4 + j;               // == (e8*8 + r) & 7
        #pragma unroll
        for (int et = 0; et < 4; ++et) {
          float hn = (h[et] - mean) * rs * gam[et] + bet[et];
          *(short*)(FLAT8 + r * 640 + (((wv * 64 + et * 16 + r15) * 2) ^ (r << 4))) = f2bs(hn);
        }
      }
    }
    __syncthreads();

    // coalesced copy: 8 rows x 640 B = 5120 B = 320 threads x 16 B
    *(f32x4*)(xg + (size_t)(rowBase + e8 * 8) * 640 + tid * 16) =
        *(const f32x4*)(FLAT8 + tid * 16);
  }
}

// ================= kernel B: MLP via MFMA (proven round 3/5) =================
__global__ __launch_bounds__(512) void ace_mlp(
    const char* __restrict__ xg,
    const short* __restrict__ W1F, const short* __restrict__ W2F,
    const float* __restrict__ b1, const float* __restrict__ b2,
    float* __restrict__ out)
{
  __shared__ char smem[81920];
  const int tid  = threadIdx.x;
  const int wave = tid >> 6;     // 0..7
  const int lane = tid & 63;
  const int r15 = lane & 15, g4 = lane >> 4;
  const size_t rowBase = (size_t)blockIdx.x * BROWS;

  {
    const char* src = xg + rowBase * 640;
    #pragma unroll
    for (int i = 0; i < 10; ++i) {
      const int off = i * 8192 + wave * 1024;
      GLOAD_LDS16(src + off + lane * 16, smem + off);
    }
  }
  __syncthreads();

  f32x4 acc1[8][2] = {};
  for (int kk = 0; kk < 10; ++kk) {
    short8 b[2];
    #pragma unroll
    for (int nt = 0; nt < 2; ++nt)
      b[nt] = *(const short8*)(W1F + (((wave * 2 + nt) * 10 + kk) * 64 + lane) * 8);
    #pragma unroll
    for (int mt = 0; mt < 8; ++mt) {
      const int row = mt * 16 + r15;
      short8 a = *(const short8*)(smem + row * 640 + ((kk * 64 + g4 * 16) ^ ((row & 7) << 4)));
      #pragma unroll
      for (int nt = 0; nt < 2; ++nt)
        acc1[mt][nt] = MFMA(a, b[nt], acc1[mt][nt], 0, 0, 0);
    }
  }
  __syncthreads();

  #pragma unroll
  for (int nt = 0; nt < 2; ++nt) {
    const int c = wave * 32 + nt * 16 + r15;
    const float bias = b1[c];
    #pragma unroll
    for (int mt = 0; mt < 8; ++mt)
      #pragma unroll
      for (int j = 0; j < 4; ++j) {
        const int row = mt * 16 + g4 * 4 + j;
        *(short*)(smem + row * 512 + ((c * 2) ^ ((row & 7) << 4))) =
            f2bs(fmaxf(acc1[mt][nt][j] + bias, 0.0f));
      }
  }
  __syncthreads();

  const int nOwn2 = (wave < 2) ? 2 : 1;
  f32x4 acc2[2][8] = {};
  for (int kk = 0; kk < 8; ++kk) {
    short8 b0 = *(const short8*)(W2F + ((wave * 8 + kk) * 64 + lane) * 8);
    short8 b1f = (wave < 2)
        ? *(const short8*)(W2F + (((8 + wave) * 8 + kk) * 64 + lane) * 8) : short8{};
    #pragma unroll
    for (int mt = 0; mt < 8; ++mt) {
      const int row = mt * 16 + r15;
      short8 a = *(const short8*)(smem + row * 512 + ((kk * 64 + g4 * 16) ^ ((row & 7) << 4)));
      acc2[0][mt] = MFMA(a, b0, acc2[0][mt], 0, 0, 0);
      if (wave < 2)
        acc2[1][mt] = MFMA(a, b1f, acc2[1][mt], 0, 0, 0);
    }
  }
  __syncthreads();

  #pragma unroll
  for (int t = 0; t < 2; ++t) {
    if (t < nOwn2) {
      const int c = ((t == 0) ? wave : 8 + wave) * 16 + r15;
      const float bias = b2[c];
      #pragma unroll
      for (int mt = 0; mt < 8; ++mt)
        #pragma unroll
        for (int j = 0; j < 4; ++j) {
          const int row = mt * 16 + g4 * 4 + j;
          *(float*)(smem + (row * 160 + c) * 4) = fmaxf(acc2[t][mt][j] + bias, 0.0f);
        }
    }
  }
  __syncthreads();

  {
    f32x4* dst = (f32x4*)(out + rowBase * 160);
    const f32x4* s4 = (const f32x4*)smem;
    #pragma unroll
    for (int i = 0; i < 10; ++i)
      dst[i * 512 + tid] = s4[i * 512 + tid];
  }
}

extern "C" void kernel_launch(void* const* d_in, const int* in_sizes, int n_in,
                              void* d_out, int out_size, void* d_ws, size_t ws_size,
                              hipStream_t stream) {
  const float* visual  = (const float*)d_in[0];
  const float* audio   = (const float*)d_in[1];
  const float* pose    = (const float*)d_in[2];
  const float* spatial = (const float*)d_in[3];
  const float* timex   = (const float*)d_in[4];
  const float* Wv_p = (const float*)d_in[5];  const float* bv_p = (const float*)d_in[6];
  const float* Wa_p = (const float*)d_in[7];  const float* ba_p = (const float*)d_in[8];
  const float* Wp_p = (const float*)d_in[9];  const float* bp_p = (const float*)d_in[10];
  const float* Ws_p = (const float*)d_in[11]; const float* bs_p = (const float*)d_in[12];
  const float* Wt_p = (const float*)d_in[13]; const float* bt_p = (const float*)d_in[14];
  const float* Wv_u = (const float*)d_in[15]; const float* bv_u = (const float*)d_in[16];
  const float* Wa_u = (const float*)d_in[17]; const float* ba_u = (const float*)d_in[18];
  const float* Wp_u = (const float*)d_in[19]; const float* bp_u = (const float*)d_in[20];
  const float* Ws_u = (const float*)d_in[21]; const float* bs_u = (const float*)d_in[22];
  const float* Wt_u = (const float*)d_in[23]; const float* bt_u = (const float*)d_in[24];
  const float* Wq  = (const float*)d_in[25];  const float* bq  = (const float*)d_in[26];
  const float* Wk  = (const float*)d_in[27];  const float* bk  = (const float*)d_in[28];
  const float* Wvv = (const float*)d_in[29];  const float* bvv = (const float*)d_in[30];
  const float* Wo  = (const float*)d_in[31];  const float* bo  = (const float*)d_in[32];
  const float* gamma = (const float*)d_in[33]; const float* beta = (const float*)d_in[34];
  const float* W1 = (const float*)d_in[35];   const float* b1 = (const float*)d_in[36];
  const float* W2 = (const float*)d_in[37];   const float* b2 = (const float*)d_in[38];
  float* out = (float*)d_out;

  short* WS = (short*)d_ws;                        // bf16 tables, bytes [0, 704512)
  float* FB = (float*)((char*)d_ws + 704512);      // f32 tables, 1440 floats
  char*  xg = (char*)d_ws + 720896;                // bf16 [NROWS][320] pre-swizzled, 80 MiB

  hipLaunchKernelGGL(pack_weights, dim3(480), dim3(256), 0, stream, W1, W2, WS);
  hipLaunchKernelGGL(pack2, dim3(902), dim3(256), 0, stream,
                     Wv_p, Wa_p, Wp_p, Ws_p, Wt_p,
                     bv_p, ba_p, bp_p, bs_p, bt_p,
                     Wv_u, Wa_u, Wp_u, Ws_u, Wt_u,
                     bv_u, ba_u, bp_u, bs_u, bt_u,
                     Wq, Wk, Wvv, bq, bk, bvv, Wo, bo, WS, FB);

  hipLaunchKernelGGL(ace_front2, dim3(NROWS / 64), dim3(320), 0, stream,
                     visual, audio, pose, spatial, timex,
                     gamma, beta, WS, FB, xg);

  hipLaunchKernelGGL(ace_mlp, dim3(NROWS / BROWS), dim3(512), 0, stream,
                     xg, WS, WS + 81920, b1, b2, out);
}

// Round 10
// 510.881 us; speedup vs baseline: 2.4344x; 2.4344x over previous
//
#include <hip/hip_runtime.h>
#include <hip/hip_bf16.h>
#include <math.h>

// Round 10: round-5 VALU front with f16 weights via v_dot2_f32_f16 (f32 accum),
// QKV computed from x with the shared Wq/Wk/Wv table (reused across 5 tokens + M rows).
//  pack_weights: W1,W2 -> bf16 MFMA B-frag tables (proven)
//  pack16:       front weights -> f16 chunk-of-4 tables
//  ace_front3:   branches + QKV + attn + Wo + LN, fp32 accum / f16 data -> xg bf16 (pre-swizzled)
//  ace_mlp:      proven MFMA MLP
// B=131072, E=64, H=4, D=16, S=5. Out: (B,160) fp32.

#define NROWS 131072
#define M 2
#define WAVES 4
#define BROWS 128

typedef __attribute__((ext_vector_type(8))) short short8;
typedef __attribute__((ext_vector_type(4))) float f32x4;
typedef __attribute__((ext_vector_type(4))) _Float16 half4;
typedef __attribute__((ext_vector_type(2))) _Float16 half2;

__device__ __forceinline__ short f2bs(float f) {
  __hip_bfloat16 h = __float2bfloat16(f);
  return *reinterpret_cast<short*>(&h);
}

__device__ __forceinline__ float dot4(half4 a, half4 b, float c) {
#if __has_builtin(__builtin_amdgcn_fdot2)
  c = __builtin_amdgcn_fdot2(__builtin_shufflevector(a, a, 0, 1),
                             __builtin_shufflevector(b, b, 0, 1), c, false);
  c = __builtin_amdgcn_fdot2(__builtin_shufflevector(a, a, 2, 3),
                             __builtin_shufflevector(b, b, 2, 3), c, false);
#else
  c += (float)a.x * (float)b.x; c += (float)a.y * (float)b.y;
  c += (float)a.z * (float)b.z; c += (float)a.w * (float)b.w;
#endif
  return c;
}

#define MFMA __builtin_amdgcn_mfma_f32_16x16x32_bf16
#define GLOAD_LDS16(g, l) __builtin_amdgcn_global_load_lds( \
    (const __attribute__((address_space(1))) void*)(g),     \
    (__attribute__((address_space(3))) void*)(l), 16, 0, 0)

// f16 table layout (element offsets): WPT 0, WUT 3776, WQKV 14016, WOT 26304, total 30400
#define OFF_WUT16  3776
#define OFF_WQKV16 14016
#define OFF_WOT16  26304
#define WT_TOTAL   30400

// ---------------- pack 1: W1,W2 -> bf16 fragment-ordered (proven) ----------------
__global__ void pack_weights(const float* __restrict__ W1, const float* __restrict__ W2,
                             short* __restrict__ ws) {
  int idx = blockIdx.x * blockDim.x + threadIdx.x;
  if (idx < 81920) {
    int i = idx & 7, lane = (idx >> 3) & 63;
    int t = idx >> 9;                 // ntg*10 + kk
    int kk = t % 10, ntg = t / 10;
    int n = ntg * 16 + (lane & 15);
    int k = kk * 32 + (lane >> 4) * 8 + i;
    ws[idx] = f2bs(W1[k * 256 + n]);
  } else if (idx < 81920 + 40960) {
    int j = idx - 81920;
    int i = j & 7, lane = (j >> 3) & 63;
    int t = j >> 9;                   // ntg*8 + kk
    int kk = t & 7, ntg = t >> 3;
    int n = ntg * 16 + (lane & 15);
    int k = kk * 32 + (lane >> 4) * 8 + i;
    ws[81920 + j] = f2bs(W2[k * 160 + n]);
  }
}

// ---------------- pack 16: f16 front tables, chunk-of-4 over K ----------------
// WPT[s][ic][j<hid][c]   = Wp_s[(ic*4+c)*hid + j], zero-padded over i>=IN_s
// WUT[s][jc][e<64][c]    = Wu_s[(jc*4+c)*64 + e]
// WQKV[t][ec][hd<64][c]  = W_{q,k,v}[(ec*4+c)*64 + hd]
// WOT[hdc][e<64][c]      = Wo[(hdc*4+c)*64 + e]
__global__ void pack16(
    const float* __restrict__ Wv_p, const float* __restrict__ Wa_p,
    const float* __restrict__ Wp_p, const float* __restrict__ Ws_p,
    const float* __restrict__ Wt_p,
    const float* __restrict__ Wv_u, const float* __restrict__ Wa_u,
    const float* __restrict__ Wp_u, const float* __restrict__ Ws_u,
    const float* __restrict__ Wt_u,
    const float* __restrict__ Wq, const float* __restrict__ Wk,
    const float* __restrict__ Wvv, const float* __restrict__ Wo,
    _Float16* __restrict__ wt)
{
  int idx = blockIdx.x * blockDim.x + threadIdx.x;
  if (idx >= WT_TOTAL) return;
  const float* WP[5] = {Wv_p, Wa_p, Wp_p, Ws_p, Wt_p};
  const float* WU[5] = {Wv_u, Wa_u, Wp_u, Ws_u, Wt_u};
  const float* WT3[3] = {Wq, Wk, Wvv};
  const int INs[5]  = {14, 17, 51, 7, 10};
  const int HIDs[5] = {32, 64, 32, 16, 16};
  const int ICNT[5] = {4, 5, 13, 2, 3};
  const int JCNT[5] = {8, 16, 8, 4, 4};
  float val = 0.f;
  if (idx < OFF_WUT16) {
    int r = idx, s = 0;
    while (r >= ICNT[s] * HIDs[s] * 4) { r -= ICNT[s] * HIDs[s] * 4; ++s; }
    int ic = r / (HIDs[s] * 4);
    int j  = (r / 4) % HIDs[s];
    int c  = r & 3;
    int i  = ic * 4 + c;
    val = (i < INs[s]) ? WP[s][i * HIDs[s] + j] : 0.f;
  } else if (idx < OFF_WQKV16) {
    int r = idx - OFF_WUT16, s = 0;
    while (r >= JCNT[s] * 256) { r -= JCNT[s] * 256; ++s; }
    int jc = r / 256;
    int e  = (r / 4) & 63;
    int c  = r & 3;
    val = WU[s][(jc * 4 + c) * 64 + e];
  } else if (idx < OFF_WOT16) {
    int r = idx - OFF_WQKV16;
    int t = r >> 12;
    int r2 = r & 4095;
    int ec = r2 >> 8;
    int hd = (r2 >> 2) & 63;
    int c  = r2 & 3;
    val = WT3[t][(ec * 4 + c) * 64 + hd];
  } else {
    int r = idx - OFF_WOT16;
    int hdc = r >> 8;
    int e   = (r >> 2) & 63;
    int c   = r & 3;
    val = Wo[(hdc * 4 + c) * 64 + e];
  }
  wt[idx] = (_Float16)val;
}

// ================= kernel A: front, f16 dot2, M=2 rows/wave, no barriers =================
__global__ __launch_bounds__(256, 4) void ace_front3(
    const float* __restrict__ visual, const float* __restrict__ audio,
    const float* __restrict__ pose,   const float* __restrict__ spatial,
    const float* __restrict__ timex,
    const float* __restrict__ bv_p, const float* __restrict__ ba_p,
    const float* __restrict__ bp_p, const float* __restrict__ bs_p,
    const float* __restrict__ bt_p,
    const float* __restrict__ bv_u, const float* __restrict__ ba_u,
    const float* __restrict__ bp_u, const float* __restrict__ bs_u,
    const float* __restrict__ bt_u,
    const float* __restrict__ bq, const float* __restrict__ bk,
    const float* __restrict__ bvv, const float* __restrict__ bo,
    const float* __restrict__ gamma, const float* __restrict__ beta,
    const _Float16* __restrict__ WT,
    char* __restrict__ xg)   // bf16 [NROWS][320], byte (col*2)^((row&7)<<4)
{
  // per-wave f16 LDS (1920 elems = 3840 B):
  //   in  @0    [m][112]  (padded gaps zeroed)
  //   h   @224  [m][160]
  //   x   @544  [m][5][64]
  //   o   @1184 [m][5][64]
  __shared__ __align__(16) _Float16 lds[WAVES][1920];
  const int tid  = threadIdx.x;
  const int wave = tid >> 6;
  const int lane = tid & 63;
  _Float16* A = lds[wave];
  _Float16* Hh = A + 224;
  _Float16* X = A + 544;
  _Float16* O = A + 1184;
  const int rowBase = (blockIdx.x * WAVES + wave) * M;

  const int HIDs[5] = {32, 64, 32, 16, 16};
  const int ICNT[5] = {4, 5, 13, 2, 3};
  const int JCNT[5] = {8, 16, 8, 4, 4};
  const int IOFF[5] = {0, 16, 36, 92, 100};
  const int HOFF[5] = {0, 32, 96, 128, 144};
  const int WPT_OFF[5] = {0, 512, 1792, 3456, 3584};
  const int WUT_OFF[5] = {0, 2048, 6144, 8192, 9216};
  const float* BP[5] = {bv_p, ba_p, bp_p, bs_p, bt_p};
  const float* BU[5] = {bv_u, ba_u, bp_u, bs_u, bt_u};

  // ---- zero padded input region [0..224), then stage raw inputs as f16 ----
  #pragma unroll
  for (int k2 = 0; k2 < 4; ++k2) {
    const int idx = k2 * 64 + lane;
    if (idx < 224) A[idx] = (_Float16)0.f;
  }
  #pragma unroll
  for (int m = 0; m < M; ++m) {
    const int r = rowBase + m;
    if (lane < 14) A[m * 112 +   0 + lane] = (_Float16)visual [r * 14 + lane];
    if (lane < 17) A[m * 112 +  16 + lane] = (_Float16)audio  [r * 17 + lane];
    if (lane < 51) A[m * 112 +  36 + lane] = (_Float16)pose   [r * 51 + lane];
    if (lane <  7) A[m * 112 +  92 + lane] = (_Float16)spatial[r *  7 + lane];
    if (lane < 10) A[m * 112 + 100 + lane] = (_Float16)timex  [r * 10 + lane];
  }

  // ---- proj (relu) + upsample per modality ----
  #pragma unroll
  for (int s = 0; s < 5; ++s) {
    const int hid = HIDs[s];
    if (lane < hid) {
      const float bp = BP[s][lane];
      float a0 = bp, a1 = bp;
      const _Float16* wp = WT + WPT_OFF[s];
      #pragma unroll
      for (int ic = 0; ic < ICNT[s]; ++ic) {
        half4 w = *(const half4*)(wp + (ic * hid + lane) * 4);
        half4 v0 = *(const half4*)(A + 0 * 112 + IOFF[s] + ic * 4);
        half4 v1 = *(const half4*)(A + 1 * 112 + IOFF[s] + ic * 4);
        a0 = dot4(v0, w, a0);
        a1 = dot4(v1, w, a1);
      }
      Hh[0 * 160 + HOFF[s] + lane] = (_Float16)fmaxf(a0, 0.f);
      Hh[1 * 160 + HOFF[s] + lane] = (_Float16)fmaxf(a1, 0.f);
    }
    // upsample: all 64 lanes, lane = e
    {
      const float bu = BU[s][lane];
      float x0 = bu, x1 = bu;
      const _Float16* wu = WT + OFF_WUT16 + WUT_OFF[s];
      #pragma unroll
      for (int jc = 0; jc < JCNT[s]; ++jc) {
        half4 w = *(const half4*)(wu + (jc * 64 + lane) * 4);
        half4 h0 = *(const half4*)(Hh + 0 * 160 + HOFF[s] + jc * 4);
        half4 h1 = *(const half4*)(Hh + 1 * 160 + HOFF[s] + jc * 4);
        x0 = dot4(h0, w, x0);
        x1 = dot4(h1, w, x1);
      }
      X[0 * 320 + s * 64 + lane] = (_Float16)x0;
      X[1 * 320 + s * 64 + lane] = (_Float16)x1;
    }
  }

  // ---- QKV from x with shared Wq/Wk/Wv (lane = h*16+d); weights reused over 5 tokens x M rows ----
  float qr[M][5], kr[M][5], vr[M][5];
  {
    const float bqv = bq[lane], bkv = bk[lane], bvv_ = bvv[lane];
    #pragma unroll
    for (int m = 0; m < M; ++m)
      #pragma unroll
      for (int s = 0; s < 5; ++s) { qr[m][s] = bqv; kr[m][s] = bkv; vr[m][s] = bvv_; }
    const _Float16* wq0 = WT + OFF_WQKV16;
    #pragma unroll
    for (int ec = 0; ec < 16; ++ec) {
      half4 wq = *(const half4*)(wq0 + ((0 * 16 + ec) * 64 + lane) * 4);
      half4 wk = *(const half4*)(wq0 + ((1 * 16 + ec) * 64 + lane) * 4);
      half4 wv = *(const half4*)(wq0 + ((2 * 16 + ec) * 64 + lane) * 4);
      #pragma unroll
      for (int m = 0; m < M; ++m)
        #pragma unroll
        for (int s = 0; s < 5; ++s) {
          half4 xv = *(const half4*)(X + m * 320 + s * 64 + ec * 4);
          qr[m][s] = dot4(xv, wq, qr[m][s]);
          kr[m][s] = dot4(xv, wk, kr[m][s]);
          vr[m][s] = dot4(xv, wv, vr[m][s]);
        }
    }
  }

  // ---- attention in registers (16-lane group reduce over d), f32 ----
  float orr[M][5];
  #pragma unroll
  for (int m = 0; m < M; ++m) {
    #pragma unroll
    for (int qi = 0; qi < 5; ++qi) {
      float sc[5];
      #pragma unroll
      for (int ki = 0; ki < 5; ++ki) {
        float p = qr[m][qi] * kr[m][ki];
        p += __shfl_xor(p, 1); p += __shfl_xor(p, 2);
        p += __shfl_xor(p, 4); p += __shfl_xor(p, 8);
        sc[ki] = p * 0.25f;
      }
      float mx = fmaxf(fmaxf(fmaxf(sc[0], sc[1]), fmaxf(sc[2], sc[3])), sc[4]);
      float ssum = 0.f;
      #pragma unroll
      for (int ki = 0; ki < 5; ++ki) { sc[ki] = __expf(sc[ki] - mx); ssum += sc[ki]; }
      const float inv = 1.0f / ssum;
      float acc = 0.f;
      #pragma unroll
      for (int ki = 0; ki < 5; ++ki) acc += (sc[ki] * inv) * vr[m][ki];
      orr[m][qi] = acc;
    }
  }

  // ---- stage o as f16 ----
  #pragma unroll
  for (int m = 0; m < M; ++m)
    #pragma unroll
    for (int s = 0; s < 5; ++s) O[m * 320 + s * 64 + lane] = (_Float16)orr[m][s];

  // ---- output projection (lane = e) ----
  float att[M][5];
  {
    const float bov = bo[lane];
    #pragma unroll
    for (int m = 0; m < M; ++m)
      #pragma unroll
      for (int s = 0; s < 5; ++s) att[m][s] = bov;
    const _Float16* wo0 = WT + OFF_WOT16;
    #pragma unroll
    for (int hdc = 0; hdc < 16; ++hdc) {
      half4 w = *(const half4*)(wo0 + (hdc * 64 + lane) * 4);
      #pragma unroll
      for (int m = 0; m < M; ++m)
        #pragma unroll
        for (int s = 0; s < 5; ++s) {
          half4 o4 = *(const half4*)(O + m * 320 + s * 64 + hdc * 4);
          att[m][s] = dot4(o4, w, att[m][s]);
        }
    }
  }

  // ---- residual + LayerNorm -> xg bf16 (pre-swizzled, proven round-5 pattern) ----
  {
    const float ga = gamma[lane], be = beta[lane];
    #pragma unroll
    for (int m = 0; m < M; ++m) {
      const int r = rowBase + m;
      char* rowp = xg + (size_t)r * 640;
      const int swz = (r & 7) << 4;
      #pragma unroll
      for (int s = 0; s < 5; ++s) {
        const float hv = (float)X[m * 320 + s * 64 + lane] + att[m][s];
        float s1 = hv, s2 = hv * hv;
        #pragma unroll
        for (int off = 32; off >= 1; off >>= 1) {
          s1 += __shfl_xor(s1, off);
          s2 += __shfl_xor(s2, off);
        }
        const float mean = s1 * 0.015625f;
        const float var  = s2 * 0.015625f - mean * mean;
        const float hn = (hv - mean) * rsqrtf(var + 1e-3f) * ga + be;
        *(short*)(rowp + (((s * 64 + lane) * 2) ^ swz)) = f2bs(hn);
      }
    }
  }
}

// ================= kernel B: MLP via MFMA (proven round 3/5) =================
__global__ __launch_bounds__(512) void ace_mlp(
    const char* __restrict__ xg,
    const short* __restrict__ W1F, const short* __restrict__ W2F,
    const float* __restrict__ b1, const float* __restrict__ b2,
    float* __restrict__ out)
{
  __shared__ char smem[81920];
  const int tid  = threadIdx.x;
  const int wave = tid >> 6;     // 0..7
  const int lane = tid & 63;
  const int r15 = lane & 15, g4 = lane >> 4;
  const size_t rowBase = (size_t)blockIdx.x * BROWS;

  {
    const char* src = xg + rowBase * 640;
    #pragma unroll
    for (int i = 0; i < 10; ++i) {
      const int off = i * 8192 + wave * 1024;
      GLOAD_LDS16(src + off + lane * 16, smem + off);
    }
  }
  __syncthreads();

  f32x4 acc1[8][2] = {};
  for (int kk = 0; kk < 10; ++kk) {
    short8 b[2];
    #pragma unroll
    for (int nt = 0; nt < 2; ++nt)
      b[nt] = *(const short8*)(W1F + (((wave * 2 + nt) * 10 + kk) * 64 + lane) * 8);
    #pragma unroll
    for (int mt = 0; mt < 8; ++mt) {
      const int row = mt * 16 + r15;
      short8 a = *(const short8*)(smem + row * 640 + ((kk * 64 + g4 * 16) ^ ((row & 7) << 4)));
      #pragma unroll
      for (int nt = 0; nt < 2; ++nt)
        acc1[mt][nt] = MFMA(a, b[nt], acc1[mt][nt], 0, 0, 0);
    }
  }
  __syncthreads();

  #pragma unroll
  for (int nt = 0; nt < 2; ++nt) {
    const int c = wave * 32 + nt * 16 + r15;
    const float bias = b1[c];
    #pragma unroll
    for (int mt = 0; mt < 8; ++mt)
      #pragma unroll
      for (int j = 0; j < 4; ++j) {
        const int row = mt * 16 + g4 * 4 + j;
        *(short*)(smem + row * 512 + ((c * 2) ^ ((row & 7) << 4))) =
            f2bs(fmaxf(acc1[mt][nt][j] + bias, 0.0f));
      }
  }
  __syncthreads();

  const int nOwn2 = (wave < 2) ? 2 : 1;
  f32x4 acc2[2][8] = {};
  for (int kk = 0; kk < 8; ++kk) {
    short8 b0 = *(const short8*)(W2F + ((wave * 8 + kk) * 64 + lane) * 8);
    short8 b1f = (wave < 2)
        ? *(const short8*)(W2F + (((8 + wave) * 8 + kk) * 64 + lane) * 8) : short8{};
    #pragma unroll
    for (int mt = 0; mt < 8; ++mt) {
      const int row = mt * 16 + r15;
      short8 a = *(const short8*)(smem + row * 512 + ((kk * 64 + g4 * 16) ^ ((row & 7) << 4)));
      acc2[0][mt] = MFMA(a, b0, acc2[0][mt], 0, 0, 0);
      if (wave < 2)
        acc2[1][mt] = MFMA(a, b1f, acc2[1][mt], 0, 0, 0);
    }
  }
  __syncthreads();

  #pragma unroll
  for (int t = 0; t < 2; ++t) {
    if (t < nOwn2) {
      const int c = ((t == 0) ? wave : 8 + wave) * 16 + r15;
      const float bias = b2[c];
      #pragma unroll
      for (int mt = 0; mt < 8; ++mt)
        #pragma unroll
        for (int j = 0; j < 4; ++j) {
          const int row = mt * 16 + g4 * 4 + j;
          *(float*)(smem + (row * 160 + c) * 4) = fmaxf(acc2[t][mt][j] + bias, 0.0f);
        }
    }
  }
  __syncthreads();

  {
    f32x4* dst = (f32x4*)(out + rowBase * 160);
    const f32x4* s4 = (const f32x4*)smem;
    #pragma unroll
    for (int i = 0; i < 10; ++i)
      dst[i * 512 + tid] = s4[i * 512 + tid];
  }
}

extern "C" void kernel_launch(void* const* d_in, const int* in_sizes, int n_in,
                              void* d_out, int out_size, void* d_ws, size_t ws_size,
                              hipStream_t stream) {
  const float* visual  = (const float*)d_in[0];
  const float* audio   = (const float*)d_in[1];
  const float* pose    = (const float*)d_in[2];
  const float* spatial = (const float*)d_in[3];
  const float* timex   = (const float*)d_in[4];
  const float* Wv_p = (const float*)d_in[5];  const float* bv_p = (const float*)d_in[6];
  const float* Wa_p = (const float*)d_in[7];  const float* ba_p = (const float*)d_in[8];
  const float* Wp_p = (const float*)d_in[9];  const float* bp_p = (const float*)d_in[10];
  const float* Ws_p = (const float*)d_in[11]; const float* bs_p = (const float*)d_in[12];
  const float* Wt_p = (const float*)d_in[13]; const float* bt_p = (const float*)d_in[14];
  const float* Wv_u = (const float*)d_in[15]; const float* bv_u = (const float*)d_in[16];
  const float* Wa_u = (const float*)d_in[17]; const float* ba_u = (const float*)d_in[18];
  const float* Wp_u = (const float*)d_in[19]; const float* bp_u = (const float*)d_in[20];
  const float* Ws_u = (const float*)d_in[21]; const float* bs_u = (const float*)d_in[22];
  const float* Wt_u = (const float*)d_in[23]; const float* bt_u = (const float*)d_in[24];
  const float* Wq  = (const float*)d_in[25];  const float* bq  = (const float*)d_in[26];
  const float* Wk  = (const float*)d_in[27];  const float* bk  = (const float*)d_in[28];
  const float* Wvv = (const float*)d_in[29];  const float* bvv = (const float*)d_in[30];
  const float* Wo  = (const float*)d_in[31];  const float* bo  = (const float*)d_in[32];
  const float* gamma = (const float*)d_in[33]; const float* beta = (const float*)d_in[34];
  const float* W1 = (const float*)d_in[35];   const float* b1 = (const float*)d_in[36];
  const float* W2 = (const float*)d_in[37];   const float* b2 = (const float*)d_in[38];
  float* out = (float*)d_out;

  short*     WS = (short*)d_ws;                        // bf16 MLP tables [0, 245760) B
  _Float16*  WT = (_Float16*)((char*)d_ws + 245760);   // f16 front tables, 60800 B
  char*      xg = (char*)d_ws + 524288;                // bf16 [NROWS][320] pre-swizzled, 80 MiB

  hipLaunchKernelGGL(pack_weights, dim3(480), dim3(256), 0, stream, W1, W2, WS);
  hipLaunchKernelGGL(pack16, dim3((WT_TOTAL + 255) / 256), dim3(256), 0, stream,
                     Wv_p, Wa_p, Wp_p, Ws_p, Wt_p,
                     Wv_u, Wa_u, Wp_u, Ws_u, Wt_u,
                     Wq, Wk, Wvv, Wo, WT);

  hipLaunchKernelGGL(ace_front3, dim3(NROWS / (WAVES * M)), dim3(256), 0, stream,
                     visual, audio, pose, spatial, timex,
                     bv_p, ba_p, bp_p, bs_p, bt_p,
                     bv_u, ba_u, bp_u, bs_u, bt_u,
                     bq, bk, bvv, bo, gamma, beta, WT, xg);

  hipLaunchKernelGGL(ace_mlp, dim3(NROWS / BROWS), dim3(512), 0, stream,
                     xg, WS, WS + 81920, b1, b2, out);
}